// Round 5
// baseline (137.212 us; speedup 1.0000x reference)
//
#include <hip/hip_runtime.h>

#define SS 2048
#define DD 64
#define BH 32      // B*H
#define QSCALE 0.1803368801f   // 0.125 * log2(e)
#define BUFS 8448              // per-buffer shorts: K 2x2176 | V 2x2048

typedef __attribute__((ext_vector_type(8))) short short8;
typedef __attribute__((ext_vector_type(4))) float floatx4;

__device__ __forceinline__ short f2bf(float x) {        // RNE
  union { float f; unsigned u; } un; un.f = x;
  unsigned r = (un.u + 0x7FFFu + ((un.u >> 16) & 1u)) >> 16;
  return (short)r;
}
__device__ __forceinline__ short f2bf_fast(float x) {   // round-to-nearest, 2 ops
  union { float f; unsigned u; } un; un.f = x;
  return (short)((un.u + 0x8000u) >> 16);
}
__device__ __forceinline__ float fexp2(float x) {
  return __builtin_amdgcn_exp2f(x);
}
__device__ __forceinline__ void gload16(const short* g, short* l) {
  __builtin_amdgcn_global_load_lds(
      (const __attribute__((address_space(1))) void*)g,
      (__attribute__((address_space(3))) void*)l, 16, 0, 0);
}
#define MFMA __builtin_amdgcn_mfma_f32_16x16x32_bf16

// slot c (0..31) -> physical k within 32-tile: quad=c>>3, h=(c>>2)&1, r=c&3
__device__ __forceinline__ int kperm(int c) {
  return (((c >> 2) & 1) << 4) + ((c >> 3) << 2) + (c & 3);
}

// ---------- merged pre-pass: K fp32->bf16 (same layout) + V fp32->bf16 tile-major ----------
// grid (bh, tile): linear%8 = bh%8 -> writes land in the SAME XCD L2 that
// sdpa_fused (grid x = bh) reads from.
__global__ __launch_bounds__(256) void prep_kv(const float* __restrict__ K,
                                               const float* __restrict__ V,
                                               short* __restrict__ Kbf,
                                               short* __restrict__ Vtp) {
  __shared__ short Ts[64][72];
  const int bh = blockIdx.x;
  const int r0 = blockIdx.y * 64;
  const int t  = threadIdx.x;
  // V: 64x64 fp32 tile -> bf16 in LDS
  {
    const int r = t >> 2, c = (t & 3) * 16;
    const float* g = V + ((size_t)bh * SS + r0 + r) * DD + c;
    floatx4 a = *(const floatx4*)g;
    floatx4 b = *(const floatx4*)(g + 4);
    floatx4 cc = *(const floatx4*)(g + 8);
    floatx4 dd = *(const floatx4*)(g + 12);
    short8 x0, x1;
    x0[0]=f2bf(a[0]); x0[1]=f2bf(a[1]); x0[2]=f2bf(a[2]); x0[3]=f2bf(a[3]);
    x0[4]=f2bf(b[0]); x0[5]=f2bf(b[1]); x0[6]=f2bf(b[2]); x0[7]=f2bf(b[3]);
    x1[0]=f2bf(cc[0]);x1[1]=f2bf(cc[1]);x1[2]=f2bf(cc[2]);x1[3]=f2bf(cc[3]);
    x1[4]=f2bf(dd[0]);x1[5]=f2bf(dd[1]);x1[6]=f2bf(dd[2]);x1[7]=f2bf(dd[3]);
    *(short8*)&Ts[r][c] = x0;
    *(short8*)&Ts[r][c + 8] = x1;
  }
  // K: straight convert (independent of LDS; overlaps transpose)
  {
    const size_t i = ((size_t)bh * SS + r0) * DD + (size_t)t * 16;
    floatx4 a = *(const floatx4*)(K + i);
    floatx4 b = *(const floatx4*)(K + i + 4);
    floatx4 cc = *(const floatx4*)(K + i + 8);
    floatx4 dd = *(const floatx4*)(K + i + 12);
    short8 x0, x1;
    x0[0]=f2bf(a[0]); x0[1]=f2bf(a[1]); x0[2]=f2bf(a[2]); x0[3]=f2bf(a[3]);
    x0[4]=f2bf(b[0]); x0[5]=f2bf(b[1]); x0[6]=f2bf(b[2]); x0[7]=f2bf(b[3]);
    x1[0]=f2bf(cc[0]);x1[1]=f2bf(cc[1]);x1[2]=f2bf(cc[2]);x1[3]=f2bf(cc[3]);
    x1[4]=f2bf(dd[0]);x1[5]=f2bf(dd[1]);x1[6]=f2bf(dd[2]);x1[7]=f2bf(dd[3]);
    *(short8*)(Kbf + i) = x0;
    *(short8*)(Kbf + i + 8) = x1;
  }
  __syncthreads();
  // V write-out: [bh][tile][d][32], k-permuted
  {
    const int d = t >> 2, cblk = (t & 3) * 16;
    short8 y0, y1;
    #pragma unroll
    for (int jj = 0; jj < 8; ++jj) {
      const int c0 = cblk + jj, c1 = cblk + 8 + jj;
      y0[jj] = Ts[(c0 & 32) + kperm(c0 & 31)][d];
      y1[jj] = Ts[(c1 & 32) + kperm(c1 & 31)][d];
    }
    const int kt  = (r0 + cblk) >> 5;
    const int kin = cblk & 31;           // 0 or 16
    short* o = Vtp + (((size_t)bh * 64 + kt) * 64 + d) * 32 + kin;
    *(short8*)o = y0;
    *(short8*)(o + 8) = y1;
  }
}

// per-tile compute; MODE: 0 = below diagonal, 1 = diag lower-strip (q_rel=l16),
// 2 = diag upper-strip (q_rel=l16+16)
#define TILE_COMPUTE(JJ, MODE)                                               \
  {                                                                          \
    const short* lb = bufp + (JJ) * 2176;                                    \
    const short* vb = bufp + 4352 + (JJ) * 2048;                             \
    short8 kb00 = *(const short8*)(lb + kroA);                               \
    short8 kb01 = *(const short8*)(lb + kroB);                               \
    short8 kb10 = *(const short8*)(lb + kroA + 1088);                        \
    short8 kb11 = *(const short8*)(lb + kroB + 1088);                        \
    short8 vt0 = *(const short8*)(vb + vro);                                 \
    short8 vt1 = *(const short8*)(vb + vro + 512);                           \
    short8 vt2 = *(const short8*)(vb + vro + 1024);                          \
    short8 vt3 = *(const short8*)(vb + vro + 1536);                          \
    floatx4 t0 = z, t1 = z;                                                  \
    t0 = MFMA(kb00, qa0, t0, 0, 0, 0); t0 = MFMA(kb01, qa1, t0, 0, 0, 0);    \
    t1 = MFMA(kb10, qa0, t1, 0, 0, 0); t1 = MFMA(kb11, qa1, t1, 0, 0, 0);    \
    if ((MODE) == 1) {                                                       \
      _Pragma("unroll")                                                      \
      for (int r = 0; r < 4; ++r) {                                          \
        t0[r] = (quad * 4 + r <= l16) ? t0[r] : -1e30f;                      \
        t1[r] = -1e30f;                                                      \
      }                                                                      \
    } else if ((MODE) == 2) {                                                \
      _Pragma("unroll")                                                      \
      for (int r = 0; r < 4; ++r) {                                          \
        t1[r] = (quad * 4 + r <= l16) ? t1[r] : -1e30f;                      \
      }                                                                      \
    }                                                                        \
    short8 pa;                                                               \
    _Pragma("unroll")                                                        \
    for (int r = 0; r < 4; ++r) {                                            \
      pa[r]     = f2bf_fast(fexp2(t0[r]));                                   \
      pa[4 + r] = f2bf_fast(fexp2(t1[r]));                                   \
    }                                                                        \
    sacc = MFMA(ones, pa, sacc, 0, 0, 0);                                    \
    o0 = MFMA(vt0, pa, o0, 0, 0, 0); o1 = MFMA(vt1, pa, o1, 0, 0, 0);        \
    o2 = MFMA(vt2, pa, o2, 0, 0, 0); o3 = MFMA(vt3, pa, o3, 0, 0, 0);        \
  }

// ---------- single-pass fused SDPA: 4 waves x 16 q-rows = 64-row half-tile ----------
// grid (bh=32, y=16), y = j*2 + h: block handles rows [h*64, h*64+64) of
// q-tile (15-j) then q-tile (j). Per-block work: 32 groups (h=0) / 34 (h=1)
// -> uniform runtime AND 512 blocks = 2 blocks/CU: two independent barrier
// domains per CU, so one block's vmcnt/barrier stall overlaps the other's
// compute (the quadrant R1 [2/CU, imbalanced] and R4 [balanced, 1/CU] missed).
__global__ __launch_bounds__(256, 2) void sdpa_fused(
    const float* __restrict__ Q, const short* __restrict__ Kbf,
    const short* __restrict__ Vtp, float* __restrict__ Og) {
  __shared__ __align__(16) short Sh[2][BUFS];

  const int tid  = threadIdx.x;
  const int w    = tid >> 6;              // 0..3
  const int lane = tid & 63;
  const int quad = lane >> 4;
  const int l16  = lane & 15;

  const int bh = blockIdx.x;              // linear%8 = bh%8 -> XCD-local K/V in L2
  const int y  = blockIdx.y;              // 0..15
  const int jb = y >> 1;                  // 0..7
  const int h  = y & 1;                   // half of the 128-row q-tile

  const size_t base = (size_t)bh * SS * DD;
  const short* kbase = Kbf + base;                 // [k][d], tiles contiguous
  const short* vtb   = Vtp + base;                 // [tile][d][32]

  // per-lane swizzled global source offsets (shorts) for staging
  const int kso = (lane >> 3) * 64 + (((lane & 7) ^ (lane >> 3)) * 8);
  const int vso = (lane >> 2) * 32 + (((lane & 3) ^ ((lane >> 3) & 3)) * 8);
  // swizzled ds_read offsets (shorts)
  const int kroA = (l16 >> 3) * 544 + (l16 & 7) * 64 + ((quad ^ (l16 & 7)) * 8);
  const int kroB = (l16 >> 3) * 544 + (l16 & 7) * 64 + (((quad + 4) ^ (l16 & 7)) * 8);
  const int vro  = l16 * 32 + ((quad ^ ((l16 >> 1) & 3)) * 8);

  short8 ones;
  #pragma unroll
  for (int r = 0; r < 8; ++r) ones[r] = (short)0x3F80;   // bf16 1.0
  const floatx4 z = {0.f, 0.f, 0.f, 0.f};
  const int hw = w >> 1;                  // diag tile index within last 2-tile group

  for (int phase = 0; phase < 2; ++phase) {
    const int qt = phase ? jb : (15 - jb);
    const int np = 2 * qt + 1 + h;        // 2-tile groups this phase
    const int qA = qt * 128 + h * 64 + w * 16;   // this wave's 16 q-rows

    // ---- stage group 0 -> buf 0 ----
    {
      const short* gk = kbase + w * 512 + kso;
      gload16(gk,        &Sh[0][w * 544]);
      gload16(gk + 2048, &Sh[0][2176 + w * 544]);
      const short* gv = vtb + w * 512 + vso;
      gload16(gv,        &Sh[0][4352 + w * 512]);
      gload16(gv + 2048, &Sh[0][6400 + w * 512]);
    }

    // ---- Q fragments (B-operand layout), overlap with staging latency ----
    short8 qa0, qa1;
    {
      const float* ga = Q + base + (size_t)(qA + l16) * DD + quad * 8;
      floatx4 a0 = *(const floatx4*)ga,        a1 = *(const floatx4*)(ga + 4);
      floatx4 a2 = *(const floatx4*)(ga + 32), a3 = *(const floatx4*)(ga + 36);
      #pragma unroll
      for (int r = 0; r < 4; ++r) {
        qa0[r] = f2bf(a0[r] * QSCALE); qa0[4 + r] = f2bf(a1[r] * QSCALE);
        qa1[r] = f2bf(a2[r] * QSCALE); qa1[4 + r] = f2bf(a3[r] * QSCALE);
      }
    }

    floatx4 o0 = z, o1 = z, o2 = z, o3 = z;   // O^T: q = l16, d = i*16+quad*4+r
    floatx4 sacc = z;                         // row-sum accumulator (replicated)

    int nb = 0;
    for (int p = 0; p < np; ++p) {
      // drain own DMA (issued a full compute-period ago), then sync the block
      __asm__ volatile("s_waitcnt vmcnt(0)" ::: "memory");
      __syncthreads();
      const short* bufp = Sh[nb];

      if (p + 1 < np) {
        // ---- issue next group's DMA (overlaps this group's compute) ----
        {
          const size_t go = (size_t)(p + 1) * 4096;
          const short* gk = kbase + go + w * 512 + kso;
          gload16(gk,        &Sh[nb ^ 1][w * 544]);
          gload16(gk + 2048, &Sh[nb ^ 1][2176 + w * 544]);
          const short* gv = vtb + go + w * 512 + vso;
          gload16(gv,        &Sh[nb ^ 1][4352 + w * 512]);
          gload16(gv + 2048, &Sh[nb ^ 1][6400 + w * 512]);
        }
        // hot path: both tiles strictly below every wave's diagonal
        TILE_COMPUTE(0, 0)
        TILE_COMPUTE(1, 0)
      } else {
        // last group: wave w computes jj < hw full, jj == hw diagonal;
        // strip parity (w&1) selects which 16-row half of the 32-k tile.
        #pragma unroll
        for (int jj = 0; jj < 2; ++jj) {
          if (jj < hw) {
            TILE_COMPUTE(jj, 0)
          } else if (jj == hw) {
            if (w & 1) { TILE_COMPUTE(jj, 2) }
            else       { TILE_COMPUTE(jj, 1) }
          }
        }
      }
      nb ^= 1;
    }

    // ---- normalize in-register (sacc replicated across quads/regs), write O ----
    const float inv = 1.0f / sacc[0];
    o0 *= inv; o1 *= inv; o2 *= inv; o3 *= inv;
    float* ra = Og + base + (size_t)(qA + l16) * DD + quad * 4;
    *(floatx4*)(ra)      = o0;
    *(floatx4*)(ra + 16) = o1;
    *(floatx4*)(ra + 32) = o2;
    *(floatx4*)(ra + 48) = o3;

    // all waves done reading LDS before next phase's staging overwrites buf 0
    if (phase == 0) __syncthreads();
  }
}

extern "C" void kernel_launch(void* const* d_in, const int* in_sizes, int n_in,
                              void* d_out, int out_size, void* d_ws, size_t ws_size,
                              hipStream_t stream) {
  (void)in_sizes; (void)n_in; (void)out_size; (void)ws_size;
  const float* q = (const float*)d_in[0];
  const float* k = (const float*)d_in[1];
  const float* v = (const float*)d_in[2];
  float* o = (float*)d_out;

  short* Kbf = (short*)d_ws;                               // 8 MB
  short* Vtp = Kbf + (size_t)BH * SS * DD;                 // 8 MB

  prep_kv<<<dim3(BH, SS / 64), 256, 0, stream>>>(k, v, Kbf, Vtp);
  sdpa_fused<<<dim3(BH, 16), 256, 0, stream>>>(q, Kbf, Vtp, o);
}

// Round 6
// 132.187 us; speedup vs baseline: 1.0380x; 1.0380x over previous
//
#include <hip/hip_runtime.h>

#define SS 2048
#define DD 64
#define BH 32      // B*H
#define QSCALE 0.1803368801f   // 0.125 * log2(e)
#define BUFS 8448              // per-buffer shorts: K 2x2176 | V 2x2048

typedef __attribute__((ext_vector_type(8))) short short8;
typedef __attribute__((ext_vector_type(4))) float floatx4;

__device__ __forceinline__ short f2bf(float x) {        // RNE
  union { float f; unsigned u; } un; un.f = x;
  unsigned r = (un.u + 0x7FFFu + ((un.u >> 16) & 1u)) >> 16;
  return (short)r;
}
__device__ __forceinline__ short f2bf_fast(float x) {   // round-to-nearest, 2 ops
  union { float f; unsigned u; } un; un.f = x;
  return (short)((un.u + 0x8000u) >> 16);
}
__device__ __forceinline__ float fexp2(float x) {
  return __builtin_amdgcn_exp2f(x);
}
__device__ __forceinline__ void gload16(const short* g, short* l) {
  __builtin_amdgcn_global_load_lds(
      (const __attribute__((address_space(1))) void*)g,
      (__attribute__((address_space(3))) void*)l, 16, 0, 0);
}
#define MFMA __builtin_amdgcn_mfma_f32_16x16x32_bf16

// slot c (0..31) -> physical k within 32-tile: quad=c>>3, h=(c>>2)&1, r=c&3
__device__ __forceinline__ int kperm(int c) {
  return (((c >> 2) & 1) << 4) + ((c >> 3) << 2) + (c & 3);
}

// ---------- merged pre-pass: K fp32->bf16 (same layout) + V fp32->bf16 tile-major ----------
// grid (bh, tile): linear%8 = bh%8 -> writes land in the SAME XCD L2 that
// sdpa_fused (grid x = bh) reads from.
__global__ __launch_bounds__(256) void prep_kv(const float* __restrict__ K,
                                               const float* __restrict__ V,
                                               short* __restrict__ Kbf,
                                               short* __restrict__ Vtp) {
  __shared__ short Ts[64][72];
  const int bh = blockIdx.x;
  const int r0 = blockIdx.y * 64;
  const int t  = threadIdx.x;
  // V: 64x64 fp32 tile -> bf16 in LDS
  {
    const int r = t >> 2, c = (t & 3) * 16;
    const float* g = V + ((size_t)bh * SS + r0 + r) * DD + c;
    floatx4 a = *(const floatx4*)g;
    floatx4 b = *(const floatx4*)(g + 4);
    floatx4 cc = *(const floatx4*)(g + 8);
    floatx4 dd = *(const floatx4*)(g + 12);
    short8 x0, x1;
    x0[0]=f2bf(a[0]); x0[1]=f2bf(a[1]); x0[2]=f2bf(a[2]); x0[3]=f2bf(a[3]);
    x0[4]=f2bf(b[0]); x0[5]=f2bf(b[1]); x0[6]=f2bf(b[2]); x0[7]=f2bf(b[3]);
    x1[0]=f2bf(cc[0]);x1[1]=f2bf(cc[1]);x1[2]=f2bf(cc[2]);x1[3]=f2bf(cc[3]);
    x1[4]=f2bf(dd[0]);x1[5]=f2bf(dd[1]);x1[6]=f2bf(dd[2]);x1[7]=f2bf(dd[3]);
    *(short8*)&Ts[r][c] = x0;
    *(short8*)&Ts[r][c + 8] = x1;
  }
  // K: straight convert (independent of LDS; overlaps transpose)
  {
    const size_t i = ((size_t)bh * SS + r0) * DD + (size_t)t * 16;
    floatx4 a = *(const floatx4*)(K + i);
    floatx4 b = *(const floatx4*)(K + i + 4);
    floatx4 cc = *(const floatx4*)(K + i + 8);
    floatx4 dd = *(const floatx4*)(K + i + 12);
    short8 x0, x1;
    x0[0]=f2bf(a[0]); x0[1]=f2bf(a[1]); x0[2]=f2bf(a[2]); x0[3]=f2bf(a[3]);
    x0[4]=f2bf(b[0]); x0[5]=f2bf(b[1]); x0[6]=f2bf(b[2]); x0[7]=f2bf(b[3]);
    x1[0]=f2bf(cc[0]);x1[1]=f2bf(cc[1]);x1[2]=f2bf(cc[2]);x1[3]=f2bf(cc[3]);
    x1[4]=f2bf(dd[0]);x1[5]=f2bf(dd[1]);x1[6]=f2bf(dd[2]);x1[7]=f2bf(dd[3]);
    *(short8*)(Kbf + i) = x0;
    *(short8*)(Kbf + i + 8) = x1;
  }
  __syncthreads();
  // V write-out: [bh][tile][d][32], k-permuted
  {
    const int d = t >> 2, cblk = (t & 3) * 16;
    short8 y0, y1;
    #pragma unroll
    for (int jj = 0; jj < 8; ++jj) {
      const int c0 = cblk + jj, c1 = cblk + 8 + jj;
      y0[jj] = Ts[(c0 & 32) + kperm(c0 & 31)][d];
      y1[jj] = Ts[(c1 & 32) + kperm(c1 & 31)][d];
    }
    const int kt  = (r0 + cblk) >> 5;
    const int kin = cblk & 31;           // 0 or 16
    short* o = Vtp + (((size_t)bh * 64 + kt) * 64 + d) * 32 + kin;
    *(short8*)o = y0;
    *(short8*)(o + 8) = y1;
  }
}

// per-tile compute; MODE: 0 = below diagonal, 1 = diag lower-strip (q_rel=l16),
// 2 = diag upper-strip (q_rel=l16+16)
#define TILE_COMPUTE(JJ, MODE)                                               \
  {                                                                          \
    const short* lb = bufp + (JJ) * 2176;                                    \
    const short* vb = bufp + 4352 + (JJ) * 2048;                             \
    short8 kb00 = *(const short8*)(lb + kroA);                               \
    short8 kb01 = *(const short8*)(lb + kroB);                               \
    short8 kb10 = *(const short8*)(lb + kroA + 1088);                        \
    short8 kb11 = *(const short8*)(lb + kroB + 1088);                        \
    short8 vt0 = *(const short8*)(vb + vro);                                 \
    short8 vt1 = *(const short8*)(vb + vro + 512);                           \
    short8 vt2 = *(const short8*)(vb + vro + 1024);                          \
    short8 vt3 = *(const short8*)(vb + vro + 1536);                          \
    floatx4 t0 = z, t1 = z;                                                  \
    t0 = MFMA(kb00, qa0, t0, 0, 0, 0); t0 = MFMA(kb01, qa1, t0, 0, 0, 0);    \
    t1 = MFMA(kb10, qa0, t1, 0, 0, 0); t1 = MFMA(kb11, qa1, t1, 0, 0, 0);    \
    if ((MODE) == 1) {                                                       \
      _Pragma("unroll")                                                      \
      for (int r = 0; r < 4; ++r) {                                          \
        t0[r] = (quad * 4 + r <= l16) ? t0[r] : -1e30f;                      \
        t1[r] = -1e30f;                                                      \
      }                                                                      \
    } else if ((MODE) == 2) {                                                \
      _Pragma("unroll")                                                      \
      for (int r = 0; r < 4; ++r) {                                          \
        t1[r] = (quad * 4 + r <= l16) ? t1[r] : -1e30f;                      \
      }                                                                      \
    }                                                                        \
    short8 pa;                                                               \
    _Pragma("unroll")                                                        \
    for (int r = 0; r < 4; ++r) {                                            \
      pa[r]     = f2bf_fast(fexp2(t0[r]));                                   \
      pa[4 + r] = f2bf_fast(fexp2(t1[r]));                                   \
    }                                                                        \
    sacc = MFMA(ones, pa, sacc, 0, 0, 0);                                    \
    o0 = MFMA(vt0, pa, o0, 0, 0, 0); o1 = MFMA(vt1, pa, o1, 0, 0, 0);        \
    o2 = MFMA(vt2, pa, o2, 0, 0, 0); o3 = MFMA(vt3, pa, o3, 0, 0, 0);        \
  }

// ---------- single-pass fused SDPA: 4 waves x 16 q-rows = ONE 64-row q-tile ----------
// grid (bh=32, y=32) = 1024 blocks, 33.8KB LDS + 56 VGPR + launch_bounds(256,4)
// -> 4 blocks/CU resident = 16 waves/CU = 4 waves/SIMD (R1/R4/R5 all ran <=2,
// and kernel time was invariant at ~41-43us -> latency un-hidden by TLP).
// qt = y<16 ? 31-y : y-16: under stride-8 round-robin every CU's 4-block set
// sums to exactly 66 groups: (32-y0)+(24-y0)+(y0+1)+(y0+9) = 66 for all y0.
__global__ __launch_bounds__(256, 4) void sdpa_fused(
    const float* __restrict__ Q, const short* __restrict__ Kbf,
    const short* __restrict__ Vtp, float* __restrict__ Og) {
  __shared__ __align__(16) short Sh[2][BUFS];

  const int tid  = threadIdx.x;
  const int w    = tid >> 6;              // 0..3
  const int lane = tid & 63;
  const int quad = lane >> 4;
  const int l16  = lane & 15;

  const int bh = blockIdx.x;              // linear%8 = bh%8 -> XCD-local K/V in L2
  const int y  = blockIdx.y;              // 0..31
  const int qt = (y < 16) ? (31 - y) : (y - 16);   // 64-row q-tile index

  const size_t base = (size_t)bh * SS * DD;
  const short* kbase = Kbf + base;                 // [k][d], tiles contiguous
  const short* vtb   = Vtp + base;                 // [tile][d][32]

  // per-lane swizzled global source offsets (shorts) for staging
  const int kso = (lane >> 3) * 64 + (((lane & 7) ^ (lane >> 3)) * 8);
  const int vso = (lane >> 2) * 32 + (((lane & 3) ^ ((lane >> 3) & 3)) * 8);
  // swizzled ds_read offsets (shorts)
  const int kroA = (l16 >> 3) * 544 + (l16 & 7) * 64 + ((quad ^ (l16 & 7)) * 8);
  const int kroB = (l16 >> 3) * 544 + (l16 & 7) * 64 + (((quad + 4) ^ (l16 & 7)) * 8);
  const int vro  = l16 * 32 + ((quad ^ ((l16 >> 1) & 3)) * 8);

  short8 ones;
  #pragma unroll
  for (int r = 0; r < 8; ++r) ones[r] = (short)0x3F80;   // bf16 1.0
  const floatx4 z = {0.f, 0.f, 0.f, 0.f};
  const int hw = w >> 1;                  // diag tile index within last 2-tile group

  const int np = qt + 1;                  // 2-tile groups (k extent = 2qt+2 tiles)
  const int qA = qt * 64 + w * 16;        // this wave's 16 q-rows

  // ---- stage group 0 -> buf 0 ----
  {
    const short* gk = kbase + w * 512 + kso;
    gload16(gk,        &Sh[0][w * 544]);
    gload16(gk + 2048, &Sh[0][2176 + w * 544]);
    const short* gv = vtb + w * 512 + vso;
    gload16(gv,        &Sh[0][4352 + w * 512]);
    gload16(gv + 2048, &Sh[0][6400 + w * 512]);
  }

  // ---- Q fragments (B-operand layout), overlap with staging latency ----
  short8 qa0, qa1;
  {
    const float* ga = Q + base + (size_t)(qA + l16) * DD + quad * 8;
    floatx4 a0 = *(const floatx4*)ga,        a1 = *(const floatx4*)(ga + 4);
    floatx4 a2 = *(const floatx4*)(ga + 32), a3 = *(const floatx4*)(ga + 36);
    #pragma unroll
    for (int r = 0; r < 4; ++r) {
      qa0[r] = f2bf(a0[r] * QSCALE); qa0[4 + r] = f2bf(a1[r] * QSCALE);
      qa1[r] = f2bf(a2[r] * QSCALE); qa1[4 + r] = f2bf(a3[r] * QSCALE);
    }
  }

  floatx4 o0 = z, o1 = z, o2 = z, o3 = z;   // O^T: q = l16, d = i*16+quad*4+r
  floatx4 sacc = z;                         // row-sum accumulator (replicated)

  int nb = 0;
  for (int p = 0; p < np; ++p) {
    // drain own DMA (issued a full compute-period ago), then sync the block
    __asm__ volatile("s_waitcnt vmcnt(0)" ::: "memory");
    __syncthreads();
    const short* bufp = Sh[nb];

    if (p + 1 < np) {
      // ---- issue next group's DMA (overlaps this group's compute) ----
      {
        const size_t go = (size_t)(p + 1) * 4096;
        const short* gk = kbase + go + w * 512 + kso;
        gload16(gk,        &Sh[nb ^ 1][w * 544]);
        gload16(gk + 2048, &Sh[nb ^ 1][2176 + w * 544]);
        const short* gv = vtb + go + w * 512 + vso;
        gload16(gv,        &Sh[nb ^ 1][4352 + w * 512]);
        gload16(gv + 2048, &Sh[nb ^ 1][6400 + w * 512]);
      }
      // hot path: both tiles strictly below every wave's diagonal
      TILE_COMPUTE(0, 0)
      TILE_COMPUTE(1, 0)
    } else {
      // last group: wave w computes jj < hw full, jj == hw diagonal;
      // strip parity (w&1) selects which 16-row half of the 32-k tile.
      #pragma unroll
      for (int jj = 0; jj < 2; ++jj) {
        if (jj < hw) {
          TILE_COMPUTE(jj, 0)
        } else if (jj == hw) {
          if (w & 1) { TILE_COMPUTE(jj, 2) }
          else       { TILE_COMPUTE(jj, 1) }
        }
      }
    }
    nb ^= 1;
  }

  // ---- normalize in-register (sacc replicated across quads/regs), write O ----
  const float inv = 1.0f / sacc[0];
  o0 *= inv; o1 *= inv; o2 *= inv; o3 *= inv;
  float* ra = Og + base + (size_t)(qA + l16) * DD + quad * 4;
  *(floatx4*)(ra)      = o0;
  *(floatx4*)(ra + 16) = o1;
  *(floatx4*)(ra + 32) = o2;
  *(floatx4*)(ra + 48) = o3;
}

extern "C" void kernel_launch(void* const* d_in, const int* in_sizes, int n_in,
                              void* d_out, int out_size, void* d_ws, size_t ws_size,
                              hipStream_t stream) {
  (void)in_sizes; (void)n_in; (void)out_size; (void)ws_size;
  const float* q = (const float*)d_in[0];
  const float* k = (const float*)d_in[1];
  const float* v = (const float*)d_in[2];
  float* o = (float*)d_out;

  short* Kbf = (short*)d_ws;                               // 8 MB
  short* Vtp = Kbf + (size_t)BH * SS * DD;                 // 8 MB

  prep_kv<<<dim3(BH, SS / 64), 256, 0, stream>>>(k, v, Kbf, Vtp);
  sdpa_fused<<<dim3(BH, 32), 256, 0, stream>>>(q, Kbf, Vtp, o);
}

// Round 7
// 131.481 us; speedup vs baseline: 1.0436x; 1.0054x over previous
//
#include <hip/hip_runtime.h>

#define SS 2048
#define DD 64
#define BH 32      // B*H
#define QSCALE 0.1803368801f   // 0.125 * log2(e)
#define BUFS 8448              // per-buffer shorts: K 2x2176 | V 2x2048

typedef __attribute__((ext_vector_type(8))) short short8;
typedef __attribute__((ext_vector_type(4))) float floatx4;

__device__ __forceinline__ short f2bf(float x) {        // RNE
  union { float f; unsigned u; } un; un.f = x;
  unsigned r = (un.u + 0x7FFFu + ((un.u >> 16) & 1u)) >> 16;
  return (short)r;
}
__device__ __forceinline__ short f2bf_fast(float x) {   // round-to-nearest, 2 ops
  union { float f; unsigned u; } un; un.f = x;
  return (short)((un.u + 0x8000u) >> 16);
}
__device__ __forceinline__ float fexp2(float x) {
  return __builtin_amdgcn_exp2f(x);
}
__device__ __forceinline__ void gload16(const short* g, short* l) {
  __builtin_amdgcn_global_load_lds(
      (const __attribute__((address_space(1))) void*)g,
      (__attribute__((address_space(3))) void*)l, 16, 0, 0);
}
#define MFMA __builtin_amdgcn_mfma_f32_16x16x32_bf16

// slot c (0..31) -> physical k within 32-tile: quad=c>>3, h=(c>>2)&1, r=c&3
__device__ __forceinline__ int kperm(int c) {
  return (((c >> 2) & 1) << 4) + ((c >> 3) << 2) + (c & 3);
}

// ---------- merged pre-pass: K fp32->bf16 (same layout) + V fp32->bf16 tile-major ----------
// grid (bh, tile): linear%8 = bh%8 -> writes land in the SAME XCD L2 that
// sdpa_fused (grid x = bh) reads from.
__global__ __launch_bounds__(256) void prep_kv(const float* __restrict__ K,
                                               const float* __restrict__ V,
                                               short* __restrict__ Kbf,
                                               short* __restrict__ Vtp) {
  __shared__ short Ts[64][72];
  const int bh = blockIdx.x;
  const int r0 = blockIdx.y * 64;
  const int t  = threadIdx.x;
  // V: 64x64 fp32 tile -> bf16 in LDS
  {
    const int r = t >> 2, c = (t & 3) * 16;
    const float* g = V + ((size_t)bh * SS + r0 + r) * DD + c;
    floatx4 a = *(const floatx4*)g;
    floatx4 b = *(const floatx4*)(g + 4);
    floatx4 cc = *(const floatx4*)(g + 8);
    floatx4 dd = *(const floatx4*)(g + 12);
    short8 x0, x1;
    x0[0]=f2bf(a[0]); x0[1]=f2bf(a[1]); x0[2]=f2bf(a[2]); x0[3]=f2bf(a[3]);
    x0[4]=f2bf(b[0]); x0[5]=f2bf(b[1]); x0[6]=f2bf(b[2]); x0[7]=f2bf(b[3]);
    x1[0]=f2bf(cc[0]);x1[1]=f2bf(cc[1]);x1[2]=f2bf(cc[2]);x1[3]=f2bf(cc[3]);
    x1[4]=f2bf(dd[0]);x1[5]=f2bf(dd[1]);x1[6]=f2bf(dd[2]);x1[7]=f2bf(dd[3]);
    *(short8*)&Ts[r][c] = x0;
    *(short8*)&Ts[r][c + 8] = x1;
  }
  // K: straight convert (independent of LDS; overlaps transpose)
  {
    const size_t i = ((size_t)bh * SS + r0) * DD + (size_t)t * 16;
    floatx4 a = *(const floatx4*)(K + i);
    floatx4 b = *(const floatx4*)(K + i + 4);
    floatx4 cc = *(const floatx4*)(K + i + 8);
    floatx4 dd = *(const floatx4*)(K + i + 12);
    short8 x0, x1;
    x0[0]=f2bf(a[0]); x0[1]=f2bf(a[1]); x0[2]=f2bf(a[2]); x0[3]=f2bf(a[3]);
    x0[4]=f2bf(b[0]); x0[5]=f2bf(b[1]); x0[6]=f2bf(b[2]); x0[7]=f2bf(b[3]);
    x1[0]=f2bf(cc[0]);x1[1]=f2bf(cc[1]);x1[2]=f2bf(cc[2]);x1[3]=f2bf(cc[3]);
    x1[4]=f2bf(dd[0]);x1[5]=f2bf(dd[1]);x1[6]=f2bf(dd[2]);x1[7]=f2bf(dd[3]);
    *(short8*)(Kbf + i) = x0;
    *(short8*)(Kbf + i + 8) = x1;
  }
  __syncthreads();
  // V write-out: [bh][tile][d][32], k-permuted
  {
    const int d = t >> 2, cblk = (t & 3) * 16;
    short8 y0, y1;
    #pragma unroll
    for (int jj = 0; jj < 8; ++jj) {
      const int c0 = cblk + jj, c1 = cblk + 8 + jj;
      y0[jj] = Ts[(c0 & 32) + kperm(c0 & 31)][d];
      y1[jj] = Ts[(c1 & 32) + kperm(c1 & 31)][d];
    }
    const int kt  = (r0 + cblk) >> 5;
    const int kin = cblk & 31;           // 0 or 16
    short* o = Vtp + (((size_t)bh * 64 + kt) * 64 + d) * 32 + kin;
    *(short8*)o = y0;
    *(short8*)(o + 8) = y1;
  }
}

// per-tile compute for TWO 16-row strips sharing K fragments.
// DIAG_=0: fully below diagonal; DIAG_=1: this wave's diagonal tile
// (strip A local q = l16, strip B local q = l16+16; tB0 is vacuously unmasked).
#define TILE32(JJ, DIAG_)                                                    \
  {                                                                          \
    const short* lb = bufp + (JJ) * 2176;                                    \
    const short* vb = bufp + 4352 + (JJ) * 2048;                             \
    short8 kb00 = *(const short8*)(lb + kroA);                               \
    short8 kb01 = *(const short8*)(lb + kroB);                               \
    short8 kb10 = *(const short8*)(lb + kroA + 1088);                        \
    short8 kb11 = *(const short8*)(lb + kroB + 1088);                        \
    short8 vt0 = *(const short8*)(vb + vro);                                 \
    short8 vt1 = *(const short8*)(vb + vro + 512);                           \
    short8 vt2 = *(const short8*)(vb + vro + 1024);                          \
    short8 vt3 = *(const short8*)(vb + vro + 1536);                          \
    floatx4 tA0 = z, tA1 = z, tB0 = z, tB1 = z;                              \
    tA0 = MFMA(kb00, qaA0, tA0, 0, 0, 0); tA0 = MFMA(kb01, qaA1, tA0, 0, 0, 0);\
    tA1 = MFMA(kb10, qaA0, tA1, 0, 0, 0); tA1 = MFMA(kb11, qaA1, tA1, 0, 0, 0);\
    tB0 = MFMA(kb00, qaB0, tB0, 0, 0, 0); tB0 = MFMA(kb01, qaB1, tB0, 0, 0, 0);\
    tB1 = MFMA(kb10, qaB0, tB1, 0, 0, 0); tB1 = MFMA(kb11, qaB1, tB1, 0, 0, 0);\
    if (DIAG_) {                                                             \
      _Pragma("unroll")                                                      \
      for (int r = 0; r < 4; ++r) {                                          \
        tA0[r] = (quad * 4 + r      <= l16) ? tA0[r] : -1e30f;               \
        tA1[r] = (quad * 4 + r + 16 <= l16) ? tA1[r] : -1e30f;               \
        tB1[r] = (quad * 4 + r      <= l16) ? tB1[r] : -1e30f;               \
      }                                                                      \
    }                                                                        \
    short8 paA, paB;                                                         \
    _Pragma("unroll")                                                        \
    for (int r = 0; r < 4; ++r) {                                            \
      paA[r]     = f2bf_fast(fexp2(tA0[r]));                                 \
      paA[4 + r] = f2bf_fast(fexp2(tA1[r]));                                 \
      paB[r]     = f2bf_fast(fexp2(tB0[r]));                                 \
      paB[4 + r] = f2bf_fast(fexp2(tB1[r]));                                 \
    }                                                                        \
    sA = MFMA(ones, paA, sA, 0, 0, 0);                                       \
    sB = MFMA(ones, paB, sB, 0, 0, 0);                                       \
    oA0 = MFMA(vt0, paA, oA0, 0, 0, 0); oA1 = MFMA(vt1, paA, oA1, 0, 0, 0);  \
    oA2 = MFMA(vt2, paA, oA2, 0, 0, 0); oA3 = MFMA(vt3, paA, oA3, 0, 0, 0);  \
    oB0 = MFMA(vt0, paB, oB0, 0, 0, 0); oB1 = MFMA(vt1, paB, oB1, 0, 0, 0);  \
    oB2 = MFMA(vt2, paB, oB2, 0, 0, 0); oB3 = MFMA(vt3, paB, oB3, 0, 0, 0);  \
  }

// ---------- single-pass fused SDPA: (qp,kp) wave split over 64-row q-tile ----------
// grid (bh=32, y=32) = 1024 blocks = 4/CU = 16 waves/CU (4/SIMD, as R6).
// NEW vs R6: wave w = (qp=w>>1, kp=w&1). qp picks 32 q-rows (2 strips, shared
// K frags); kp picks tile parity within each 2-tile group. Each wave reads ONE
// tile (8 KB) per group instead of two -> block LDS-read traffic HALVES
// (R6 audit: LDS unit ~34k cyc/CU was the largest pipe consumer).
// kp=1 partial O/sums combine into kp=0 via LDS once at the end (16 KB/block).
// Diagonal: wave's diag tile ktd = 2qt+qp has parity qp -> only kp==qp masks;
// wave (0,1) skips its tile in the last group (one idle tile, balanced).
__global__ __launch_bounds__(256, 4) void sdpa_fused(
    const float* __restrict__ Q, const short* __restrict__ Kbf,
    const short* __restrict__ Vtp, float* __restrict__ Og) {
  __shared__ __align__(16) short Sh[2][BUFS];

  const int tid  = threadIdx.x;
  const int w    = tid >> 6;              // 0..3
  const int lane = tid & 63;
  const int quad = lane >> 4;
  const int l16  = lane & 15;
  const int qp   = w >> 1;                // q-half owner
  const int kp   = w & 1;                 // k-tile parity owner

  const int bh = blockIdx.x;              // linear%8 = bh%8 -> XCD-local K/V in L2
  const int y  = blockIdx.y;              // 0..31
  const int qt = (y < 16) ? (31 - y) : (y - 16);   // 64-row q-tile index

  const size_t base = (size_t)bh * SS * DD;
  const short* kbase = Kbf + base;                 // [k][d], tiles contiguous
  const short* vtb   = Vtp + base;                 // [tile][d][32]

  // per-lane swizzled global source offsets (shorts) for staging
  const int kso = (lane >> 3) * 64 + (((lane & 7) ^ (lane >> 3)) * 8);
  const int vso = (lane >> 2) * 32 + (((lane & 3) ^ ((lane >> 3) & 3)) * 8);
  // swizzled ds_read offsets (shorts)
  const int kroA = (l16 >> 3) * 544 + (l16 & 7) * 64 + ((quad ^ (l16 & 7)) * 8);
  const int kroB = (l16 >> 3) * 544 + (l16 & 7) * 64 + (((quad + 4) ^ (l16 & 7)) * 8);
  const int vro  = l16 * 32 + ((quad ^ ((l16 >> 1) & 3)) * 8);

  short8 ones;
  #pragma unroll
  for (int r = 0; r < 8; ++r) ones[r] = (short)0x3F80;   // bf16 1.0
  const floatx4 z = {0.f, 0.f, 0.f, 0.f};

  const int np = qt + 1;                  // 2-tile groups (k extent = 2qt+2 tiles)
  const int qA = qt * 64 + qp * 32;       // strip A rows; strip B = +16
  const int qB = qA + 16;

  // ---- stage group 0 -> buf 0 (wave w stages chunk w, role-independent) ----
  {
    const short* gk = kbase + w * 512 + kso;
    gload16(gk,        &Sh[0][w * 544]);
    gload16(gk + 2048, &Sh[0][2176 + w * 544]);
    const short* gv = vtb + w * 512 + vso;
    gload16(gv,        &Sh[0][4352 + w * 512]);
    gload16(gv + 2048, &Sh[0][6400 + w * 512]);
  }

  // ---- Q fragments for both strips (B-operand layout), overlap with staging ----
  short8 qaA0, qaA1, qaB0, qaB1;
  {
    const float* ga = Q + base + (size_t)(qA + l16) * DD + quad * 8;
    const float* gb = Q + base + (size_t)(qB + l16) * DD + quad * 8;
    floatx4 a0 = *(const floatx4*)ga,        a1 = *(const floatx4*)(ga + 4);
    floatx4 a2 = *(const floatx4*)(ga + 32), a3 = *(const floatx4*)(ga + 36);
    floatx4 b0 = *(const floatx4*)gb,        b1 = *(const floatx4*)(gb + 4);
    floatx4 b2 = *(const floatx4*)(gb + 32), b3 = *(const floatx4*)(gb + 36);
    #pragma unroll
    for (int r = 0; r < 4; ++r) {
      qaA0[r] = f2bf(a0[r] * QSCALE); qaA0[4 + r] = f2bf(a1[r] * QSCALE);
      qaA1[r] = f2bf(a2[r] * QSCALE); qaA1[4 + r] = f2bf(a3[r] * QSCALE);
      qaB0[r] = f2bf(b0[r] * QSCALE); qaB0[4 + r] = f2bf(b1[r] * QSCALE);
      qaB1[r] = f2bf(b2[r] * QSCALE); qaB1[4 + r] = f2bf(b3[r] * QSCALE);
    }
  }

  floatx4 oA0 = z, oA1 = z, oA2 = z, oA3 = z;   // O^T: q = l16, d = i*16+quad*4+r
  floatx4 oB0 = z, oB1 = z, oB2 = z, oB3 = z;
  floatx4 sA = z, sB = z;                       // row-sum accumulators (replicated)

  int nb = 0;
  for (int p = 0; p < np; ++p) {
    // drain own DMA (issued a full compute-period ago), then sync the block
    __asm__ volatile("s_waitcnt vmcnt(0)" ::: "memory");
    __syncthreads();
    const short* bufp = Sh[nb];

    if (p + 1 < np) {
      // ---- issue next group's DMA (overlaps this group's compute) ----
      {
        const size_t go = (size_t)(p + 1) * 4096;
        const short* gk = kbase + go + w * 512 + kso;
        gload16(gk,        &Sh[nb ^ 1][w * 544]);
        gload16(gk + 2048, &Sh[nb ^ 1][2176 + w * 544]);
        const short* gv = vtb + go + w * 512 + vso;
        gload16(gv,        &Sh[nb ^ 1][4352 + w * 512]);
        gload16(gv + 2048, &Sh[nb ^ 1][6400 + w * 512]);
      }
      // not the last group: tile 2p+kp <= 2qt-1 < ktd -> always full
      TILE32(kp, 0)
    } else {
      // last group p=qt: tiles 2qt (kp=0), 2qt+1 (kp=1); ktd = 2qt+qp
      if (kp == qp) { TILE32(kp, 1) }          // own diagonal tile
      else if (kp < qp) { TILE32(kp, 0) }      // (qp=1,kp=0): tile 2qt full
      // (qp=0,kp=1): tile 2qt+1 entirely above diagonal -> skip
    }
    nb ^= 1;
  }

  // ---- cross-wave combine: kp=1 partials -> kp=0 via LDS (K/V bufs are dead) ----
  __syncthreads();                        // everyone done reading K/V LDS
  float* lf = (float*)&Sh[0][0];          // 17 KB scratch inside 33 KB LDS
  if (kp) {
    floatx4* dst = (floatx4*)&lf[qp * 2048];
    dst[0 * 64 + lane] = oA0; dst[1 * 64 + lane] = oA1;
    dst[2 * 64 + lane] = oA2; dst[3 * 64 + lane] = oA3;
    dst[4 * 64 + lane] = oB0; dst[5 * 64 + lane] = oB1;
    dst[6 * 64 + lane] = oB2; dst[7 * 64 + lane] = oB3;
    lf[4096 + qp * 128 + lane]      = sA[0];
    lf[4096 + qp * 128 + 64 + lane] = sB[0];
  }
  __syncthreads();
  if (!kp) {
    const floatx4* src = (const floatx4*)&lf[qp * 2048];
    oA0 += src[0 * 64 + lane]; oA1 += src[1 * 64 + lane];
    oA2 += src[2 * 64 + lane]; oA3 += src[3 * 64 + lane];
    oB0 += src[4 * 64 + lane]; oB1 += src[5 * 64 + lane];
    oB2 += src[6 * 64 + lane]; oB3 += src[7 * 64 + lane];
    const float invA = 1.0f / (sA[0] + lf[4096 + qp * 128 + lane]);
    const float invB = 1.0f / (sB[0] + lf[4096 + qp * 128 + 64 + lane]);
    oA0 *= invA; oA1 *= invA; oA2 *= invA; oA3 *= invA;
    oB0 *= invB; oB1 *= invB; oB2 *= invB; oB3 *= invB;
    float* ra = Og + base + (size_t)(qA + l16) * DD + quad * 4;
    float* rb = Og + base + (size_t)(qB + l16) * DD + quad * 4;
    *(floatx4*)(ra)      = oA0;
    *(floatx4*)(ra + 16) = oA1;
    *(floatx4*)(ra + 32) = oA2;
    *(floatx4*)(ra + 48) = oA3;
    *(floatx4*)(rb)      = oB0;
    *(floatx4*)(rb + 16) = oB1;
    *(floatx4*)(rb + 32) = oB2;
    *(floatx4*)(rb + 48) = oB3;
  }
}

extern "C" void kernel_launch(void* const* d_in, const int* in_sizes, int n_in,
                              void* d_out, int out_size, void* d_ws, size_t ws_size,
                              hipStream_t stream) {
  (void)in_sizes; (void)n_in; (void)out_size; (void)ws_size;
  const float* q = (const float*)d_in[0];
  const float* k = (const float*)d_in[1];
  const float* v = (const float*)d_in[2];
  float* o = (float*)d_out;

  short* Kbf = (short*)d_ws;                               // 8 MB
  short* Vtp = Kbf + (size_t)BH * SS * DD;                 // 8 MB

  prep_kv<<<dim3(BH, SS / 64), 256, 0, stream>>>(k, v, Kbf, Vtp);
  sdpa_fused<<<dim3(BH, 32), 256, 0, stream>>>(q, Kbf, Vtp, o);
}

// Round 8
// 131.062 us; speedup vs baseline: 1.0469x; 1.0032x over previous
//
#include <hip/hip_runtime.h>

#define SS 2048
#define DD 64
#define BH 32      // B*H
#define QSCALE 0.1803368801f   // 0.125 * log2(e)
#define BUFS 8448              // per-buffer shorts: K 2x2176 | V 2x2048

typedef __attribute__((ext_vector_type(8))) short short8;
typedef __attribute__((ext_vector_type(4))) float floatx4;

__device__ __forceinline__ short f2bf(float x) {        // RNE
  union { float f; unsigned u; } un; un.f = x;
  unsigned r = (un.u + 0x7FFFu + ((un.u >> 16) & 1u)) >> 16;
  return (short)r;
}
__device__ __forceinline__ float fexp2(float x) {
  return __builtin_amdgcn_exp2f(x);
}
__device__ __forceinline__ void gload16(const short* g, short* l) {
  __builtin_amdgcn_global_load_lds(
      (const __attribute__((address_space(1))) void*)g,
      (__attribute__((address_space(3))) void*)l, 16, 0, 0);
}
#define MFMA __builtin_amdgcn_mfma_f32_16x16x32_bf16

// slot c (0..31) -> physical k within 32-tile: quad=c>>3, h=(c>>2)&1, r=c&3
__device__ __forceinline__ int kperm(int c) {
  return (((c >> 2) & 1) << 4) + ((c >> 3) << 2) + (c & 3);
}

// ---------- merged pre-pass: K fp32->bf16 (same layout) + V fp32->bf16 tile-major ----------
// grid (bh, tile): linear%8 = bh%8 -> writes land in the SAME XCD L2 that
// sdpa_fused (grid x = bh) reads from.
__global__ __launch_bounds__(256) void prep_kv(const float* __restrict__ K,
                                               const float* __restrict__ V,
                                               short* __restrict__ Kbf,
                                               short* __restrict__ Vtp) {
  __shared__ short Ts[64][72];
  const int bh = blockIdx.x;
  const int r0 = blockIdx.y * 64;
  const int t  = threadIdx.x;
  // V: 64x64 fp32 tile -> bf16 in LDS
  {
    const int r = t >> 2, c = (t & 3) * 16;
    const float* g = V + ((size_t)bh * SS + r0 + r) * DD + c;
    floatx4 a = *(const floatx4*)g;
    floatx4 b = *(const floatx4*)(g + 4);
    floatx4 cc = *(const floatx4*)(g + 8);
    floatx4 dd = *(const floatx4*)(g + 12);
    short8 x0, x1;
    x0[0]=f2bf(a[0]); x0[1]=f2bf(a[1]); x0[2]=f2bf(a[2]); x0[3]=f2bf(a[3]);
    x0[4]=f2bf(b[0]); x0[5]=f2bf(b[1]); x0[6]=f2bf(b[2]); x0[7]=f2bf(b[3]);
    x1[0]=f2bf(cc[0]);x1[1]=f2bf(cc[1]);x1[2]=f2bf(cc[2]);x1[3]=f2bf(cc[3]);
    x1[4]=f2bf(dd[0]);x1[5]=f2bf(dd[1]);x1[6]=f2bf(dd[2]);x1[7]=f2bf(dd[3]);
    *(short8*)&Ts[r][c] = x0;
    *(short8*)&Ts[r][c + 8] = x1;
  }
  // K: straight convert (independent of LDS; overlaps transpose)
  {
    const size_t i = ((size_t)bh * SS + r0) * DD + (size_t)t * 16;
    floatx4 a = *(const floatx4*)(K + i);
    floatx4 b = *(const floatx4*)(K + i + 4);
    floatx4 cc = *(const floatx4*)(K + i + 8);
    floatx4 dd = *(const floatx4*)(K + i + 12);
    short8 x0, x1;
    x0[0]=f2bf(a[0]); x0[1]=f2bf(a[1]); x0[2]=f2bf(a[2]); x0[3]=f2bf(a[3]);
    x0[4]=f2bf(b[0]); x0[5]=f2bf(b[1]); x0[6]=f2bf(b[2]); x0[7]=f2bf(b[3]);
    x1[0]=f2bf(cc[0]);x1[1]=f2bf(cc[1]);x1[2]=f2bf(cc[2]);x1[3]=f2bf(cc[3]);
    x1[4]=f2bf(dd[0]);x1[5]=f2bf(dd[1]);x1[6]=f2bf(dd[2]);x1[7]=f2bf(dd[3]);
    *(short8*)(Kbf + i) = x0;
    *(short8*)(Kbf + i + 8) = x1;
  }
  __syncthreads();
  // V write-out: [bh][tile][d][32], k-permuted
  {
    const int d = t >> 2, cblk = (t & 3) * 16;
    short8 y0, y1;
    #pragma unroll
    for (int jj = 0; jj < 8; ++jj) {
      const int c0 = cblk + jj, c1 = cblk + 8 + jj;
      y0[jj] = Ts[(c0 & 32) + kperm(c0 & 31)][d];
      y1[jj] = Ts[(c1 & 32) + kperm(c1 & 31)][d];
    }
    const int kt  = (r0 + cblk) >> 5;
    const int kin = cblk & 31;           // 0 or 16
    short* o = Vtp + (((size_t)bh * 64 + kt) * 64 + d) * 32 + kin;
    *(short8*)o = y0;
    *(short8*)(o + 8) = y1;
  }
}

// pack 4 exp'd floats (lo pair from X0, hi pair from X1) into one short8 half
// via v_cvt_pk_bf16_f32 (RNE, 1 op / 2 elems; no builtin on gfx950 -> asm).
#define CVTPK(DST_, A_, B_) \
  __asm__("v_cvt_pk_bf16_f32 %0, %1, %2" : "=v"(DST_) : "v"(A_), "v"(B_))

// per-tile compute for TWO 16-row strips sharing K fragments.
// DIAG_=0: fully below diagonal; DIAG_=1: this wave's diagonal tile
// (strip A local q = l16, strip B local q = l16+16; tB0 is vacuously unmasked).
#define TILE32(JJ, DIAG_)                                                    \
  {                                                                          \
    const short* lb = bufp + (JJ) * 2176;                                    \
    const short* vb = bufp + 4352 + (JJ) * 2048;                             \
    short8 kb00 = *(const short8*)(lb + kroA);                               \
    short8 kb01 = *(const short8*)(lb + kroB);                               \
    short8 kb10 = *(const short8*)(lb + kroA + 1088);                        \
    short8 kb11 = *(const short8*)(lb + kroB + 1088);                        \
    short8 vt0 = *(const short8*)(vb + vro);                                 \
    short8 vt1 = *(const short8*)(vb + vro + 512);                           \
    short8 vt2 = *(const short8*)(vb + vro + 1024);                          \
    short8 vt3 = *(const short8*)(vb + vro + 1536);                          \
    __builtin_amdgcn_s_setprio(1);                                           \
    floatx4 tA0 = z, tA1 = z, tB0 = z, tB1 = z;                              \
    tA0 = MFMA(kb00, qaA0, tA0, 0, 0, 0); tA0 = MFMA(kb01, qaA1, tA0, 0, 0, 0);\
    tA1 = MFMA(kb10, qaA0, tA1, 0, 0, 0); tA1 = MFMA(kb11, qaA1, tA1, 0, 0, 0);\
    tB0 = MFMA(kb00, qaB0, tB0, 0, 0, 0); tB0 = MFMA(kb01, qaB1, tB0, 0, 0, 0);\
    tB1 = MFMA(kb10, qaB0, tB1, 0, 0, 0); tB1 = MFMA(kb11, qaB1, tB1, 0, 0, 0);\
    if (DIAG_) {                                                             \
      _Pragma("unroll")                                                      \
      for (int r = 0; r < 4; ++r) {                                          \
        tA0[r] = (quad * 4 + r      <= l16) ? tA0[r] : -1e30f;               \
        tA1[r] = (quad * 4 + r + 16 <= l16) ? tA1[r] : -1e30f;               \
        tB1[r] = (quad * 4 + r      <= l16) ? tB1[r] : -1e30f;               \
      }                                                                      \
    }                                                                        \
    _Pragma("unroll")                                                        \
    for (int r = 0; r < 4; ++r) {                                            \
      tA0[r] = fexp2(tA0[r]); tA1[r] = fexp2(tA1[r]);                        \
      tB0[r] = fexp2(tB0[r]); tB1[r] = fexp2(tB1[r]);                        \
    }                                                                        \
    union { unsigned u[4]; short8 s; } upA, upB;                             \
    CVTPK(upA.u[0], tA0[0], tA0[1]); CVTPK(upA.u[1], tA0[2], tA0[3]);        \
    CVTPK(upA.u[2], tA1[0], tA1[1]); CVTPK(upA.u[3], tA1[2], tA1[3]);        \
    CVTPK(upB.u[0], tB0[0], tB0[1]); CVTPK(upB.u[1], tB0[2], tB0[3]);        \
    CVTPK(upB.u[2], tB1[0], tB1[1]); CVTPK(upB.u[3], tB1[2], tB1[3]);        \
    short8 paA = upA.s, paB = upB.s;                                         \
    sA = MFMA(ones, paA, sA, 0, 0, 0);                                       \
    sB = MFMA(ones, paB, sB, 0, 0, 0);                                       \
    oA0 = MFMA(vt0, paA, oA0, 0, 0, 0); oA1 = MFMA(vt1, paA, oA1, 0, 0, 0);  \
    oA2 = MFMA(vt2, paA, oA2, 0, 0, 0); oA3 = MFMA(vt3, paA, oA3, 0, 0, 0);  \
    oB0 = MFMA(vt0, paB, oB0, 0, 0, 0); oB1 = MFMA(vt1, paB, oB1, 0, 0, 0);  \
    oB2 = MFMA(vt2, paB, oB2, 0, 0, 0); oB3 = MFMA(vt3, paB, oB3, 0, 0, 0);  \
    __builtin_amdgcn_s_setprio(0);                                           \
  }

// ---------- single-pass fused SDPA: (qp,kp) wave split over 64-row q-tile ----------
// grid (bh=32, y=32) = 1024 blocks = 4/CU = 16 waves/CU (4/SIMD).
// wave w = (qp=w>>1, kp=w&1): qp picks 32 q-rows (2 strips, shared K frags);
// kp picks tile parity in each 2-tile group (halved LDS reads, R7).
// NEW vs R7: softmax P-pack via v_cvt_pk_bf16_f32 (8 ops vs ~45 VALU ops on
// the QK->PV dependent chain) + s_setprio(1) around the MFMA/softmax core.
__global__ __launch_bounds__(256, 4) void sdpa_fused(
    const float* __restrict__ Q, const short* __restrict__ Kbf,
    const short* __restrict__ Vtp, float* __restrict__ Og) {
  __shared__ __align__(16) short Sh[2][BUFS];

  const int tid  = threadIdx.x;
  const int w    = tid >> 6;              // 0..3
  const int lane = tid & 63;
  const int quad = lane >> 4;
  const int l16  = lane & 15;
  const int qp   = w >> 1;                // q-half owner
  const int kp   = w & 1;                 // k-tile parity owner

  const int bh = blockIdx.x;              // linear%8 = bh%8 -> XCD-local K/V in L2
  const int y  = blockIdx.y;              // 0..31
  const int qt = (y < 16) ? (31 - y) : (y - 16);   // 64-row q-tile index

  const size_t base = (size_t)bh * SS * DD;
  const short* kbase = Kbf + base;                 // [k][d], tiles contiguous
  const short* vtb   = Vtp + base;                 // [tile][d][32]

  // per-lane swizzled global source offsets (shorts) for staging
  const int kso = (lane >> 3) * 64 + (((lane & 7) ^ (lane >> 3)) * 8);
  const int vso = (lane >> 2) * 32 + (((lane & 3) ^ ((lane >> 3) & 3)) * 8);
  // swizzled ds_read offsets (shorts)
  const int kroA = (l16 >> 3) * 544 + (l16 & 7) * 64 + ((quad ^ (l16 & 7)) * 8);
  const int kroB = (l16 >> 3) * 544 + (l16 & 7) * 64 + (((quad + 4) ^ (l16 & 7)) * 8);
  const int vro  = l16 * 32 + ((quad ^ ((l16 >> 1) & 3)) * 8);

  short8 ones;
  #pragma unroll
  for (int r = 0; r < 8; ++r) ones[r] = (short)0x3F80;   // bf16 1.0
  const floatx4 z = {0.f, 0.f, 0.f, 0.f};

  const int np = qt + 1;                  // 2-tile groups (k extent = 2qt+2 tiles)
  const int qA = qt * 64 + qp * 32;       // strip A rows; strip B = +16
  const int qB = qA + 16;

  // ---- stage group 0 -> buf 0 (wave w stages chunk w, role-independent) ----
  {
    const short* gk = kbase + w * 512 + kso;
    gload16(gk,        &Sh[0][w * 544]);
    gload16(gk + 2048, &Sh[0][2176 + w * 544]);
    const short* gv = vtb + w * 512 + vso;
    gload16(gv,        &Sh[0][4352 + w * 512]);
    gload16(gv + 2048, &Sh[0][6400 + w * 512]);
  }

  // ---- Q fragments for both strips (B-operand layout), overlap with staging ----
  short8 qaA0, qaA1, qaB0, qaB1;
  {
    const float* ga = Q + base + (size_t)(qA + l16) * DD + quad * 8;
    const float* gb = Q + base + (size_t)(qB + l16) * DD + quad * 8;
    floatx4 a0 = *(const floatx4*)ga,        a1 = *(const floatx4*)(ga + 4);
    floatx4 a2 = *(const floatx4*)(ga + 32), a3 = *(const floatx4*)(ga + 36);
    floatx4 b0 = *(const floatx4*)gb,        b1 = *(const floatx4*)(gb + 4);
    floatx4 b2 = *(const floatx4*)(gb + 32), b3 = *(const floatx4*)(gb + 36);
    #pragma unroll
    for (int r = 0; r < 4; ++r) {
      qaA0[r] = f2bf(a0[r] * QSCALE); qaA0[4 + r] = f2bf(a1[r] * QSCALE);
      qaA1[r] = f2bf(a2[r] * QSCALE); qaA1[4 + r] = f2bf(a3[r] * QSCALE);
      qaB0[r] = f2bf(b0[r] * QSCALE); qaB0[4 + r] = f2bf(b1[r] * QSCALE);
      qaB1[r] = f2bf(b2[r] * QSCALE); qaB1[4 + r] = f2bf(b3[r] * QSCALE);
    }
  }

  floatx4 oA0 = z, oA1 = z, oA2 = z, oA3 = z;   // O^T: q = l16, d = i*16+quad*4+r
  floatx4 oB0 = z, oB1 = z, oB2 = z, oB3 = z;
  floatx4 sA = z, sB = z;                       // row-sum accumulators (replicated)

  int nb = 0;
  for (int p = 0; p < np; ++p) {
    // drain own DMA (issued a full compute-period ago), then sync the block
    __asm__ volatile("s_waitcnt vmcnt(0)" ::: "memory");
    __syncthreads();
    const short* bufp = Sh[nb];

    if (p + 1 < np) {
      // ---- issue next group's DMA (overlaps this group's compute) ----
      {
        const size_t go = (size_t)(p + 1) * 4096;
        const short* gk = kbase + go + w * 512 + kso;
        gload16(gk,        &Sh[nb ^ 1][w * 544]);
        gload16(gk + 2048, &Sh[nb ^ 1][2176 + w * 544]);
        const short* gv = vtb + go + w * 512 + vso;
        gload16(gv,        &Sh[nb ^ 1][4352 + w * 512]);
        gload16(gv + 2048, &Sh[nb ^ 1][6400 + w * 512]);
      }
      // not the last group: tile 2p+kp <= 2qt-1 < ktd -> always full
      TILE32(kp, 0)
    } else {
      // last group p=qt: tiles 2qt (kp=0), 2qt+1 (kp=1); ktd = 2qt+qp
      if (kp == qp) { TILE32(kp, 1) }          // own diagonal tile
      else if (kp < qp) { TILE32(kp, 0) }      // (qp=1,kp=0): tile 2qt full
      // (qp=0,kp=1): tile 2qt+1 entirely above diagonal -> skip
    }
    nb ^= 1;
  }

  // ---- cross-wave combine: kp=1 partials -> kp=0 via LDS (K/V bufs are dead) ----
  __syncthreads();                        // everyone done reading K/V LDS
  float* lf = (float*)&Sh[0][0];          // 17 KB scratch inside 33 KB LDS
  if (kp) {
    floatx4* dst = (floatx4*)&lf[qp * 2048];
    dst[0 * 64 + lane] = oA0; dst[1 * 64 + lane] = oA1;
    dst[2 * 64 + lane] = oA2; dst[3 * 64 + lane] = oA3;
    dst[4 * 64 + lane] = oB0; dst[5 * 64 + lane] = oB1;
    dst[6 * 64 + lane] = oB2; dst[7 * 64 + lane] = oB3;
    lf[4096 + qp * 128 + lane]      = sA[0];
    lf[4096 + qp * 128 + 64 + lane] = sB[0];
  }
  __syncthreads();
  if (!kp) {
    const floatx4* src = (const floatx4*)&lf[qp * 2048];
    oA0 += src[0 * 64 + lane]; oA1 += src[1 * 64 + lane];
    oA2 += src[2 * 64 + lane]; oA3 += src[3 * 64 + lane];
    oB0 += src[4 * 64 + lane]; oB1 += src[5 * 64 + lane];
    oB2 += src[6 * 64 + lane]; oB3 += src[7 * 64 + lane];
    const float invA = 1.0f / (sA[0] + lf[4096 + qp * 128 + lane]);
    const float invB = 1.0f / (sB[0] + lf[4096 + qp * 128 + 64 + lane]);
    oA0 *= invA; oA1 *= invA; oA2 *= invA; oA3 *= invA;
    oB0 *= invB; oB1 *= invB; oB2 *= invB; oB3 *= invB;
    float* ra = Og + base + (size_t)(qA + l16) * DD + quad * 4;
    float* rb = Og + base + (size_t)(qB + l16) * DD + quad * 4;
    *(floatx4*)(ra)      = oA0;
    *(floatx4*)(ra + 16) = oA1;
    *(floatx4*)(ra + 32) = oA2;
    *(floatx4*)(ra + 48) = oA3;
    *(floatx4*)(rb)      = oB0;
    *(floatx4*)(rb + 16) = oB1;
    *(floatx4*)(rb + 32) = oB2;
    *(floatx4*)(rb + 48) = oB3;
  }
}

extern "C" void kernel_launch(void* const* d_in, const int* in_sizes, int n_in,
                              void* d_out, int out_size, void* d_ws, size_t ws_size,
                              hipStream_t stream) {
  (void)in_sizes; (void)n_in; (void)out_size; (void)ws_size;
  const float* q = (const float*)d_in[0];
  const float* k = (const float*)d_in[1];
  const float* v = (const float*)d_in[2];
  float* o = (float*)d_out;

  short* Kbf = (short*)d_ws;                               // 8 MB
  short* Vtp = Kbf + (size_t)BH * SS * DD;                 // 8 MB

  prep_kv<<<dim3(BH, SS / 64), 256, 0, stream>>>(k, v, Kbf, Vtp);
  sdpa_fused<<<dim3(BH, 32), 256, 0, stream>>>(q, Kbf, Vtp, o);
}